// Round 1
// baseline (1028.501 us; speedup 1.0000x reference)
//
#include <hip/hip_runtime.h>
#include <math.h>

#define B_ 256
#define A_ 196
#define R_ 1024
#define V_ 10000
#define G4 4096
#define M_ (B_ * A_)   // 50176

// ws layout in floats
#define OFF_ATTH      0
#define OFF_SCOREPART 50176
#define OFF_WEIGHT    (OFF_SCOREPART + 50176 * 4)
#define OFF_ATTRES    (OFF_WEIGHT + 50176)
#define OFF_SUMS      (OFF_ATTRES + 262144)
#define OFF_NEXTH     (OFF_SUMS + 1048576)
#define OFF_LOGITS    (OFF_NEXTH + 262144)

#define BM 64
#define BN 64
#define BK 16
#define PAD 4

// ---------------- kernel 1: att_h = prev_h @ h2a_w.T + h2a_b  [B, A] ----------
__global__ void att_h_kernel(const float* __restrict__ prev_h,
                             const float* __restrict__ h2a_w,
                             const float* __restrict__ h2a_b,
                             float* __restrict__ att_h) {
    int a = blockIdx.x;
    int b = blockIdx.y;
    int lane = threadIdx.x;
    const float* hp = prev_h + (size_t)b * R_;
    const float* wp = h2a_w + (size_t)a * R_;
    float s = 0.f;
    for (int k = lane; k < R_; k += 64) s += hp[k] * wp[k];
    for (int off = 32; off > 0; off >>= 1) s += __shfl_xor(s, off);
    if (lane == 0) att_h[b * A_ + a] = s + h2a_b[a];
}

// ---------------- kernel 2: big attention GEMM + tanh/d2d epilogue -------------
// C[m,n] = att[m,:] . a2a_w[n,:]   (m = b*A+i, n = a)
// scorepart[m, nb] = sum_{n in block} tanh(C + a2a_b[n] + att_h[m]) * d2d_w[n]
__global__ __launch_bounds__(256)
void score_gemm(const float* __restrict__ att,
                const float* __restrict__ a2a_w,
                const float* __restrict__ a2a_b,
                const float* __restrict__ d2d_w,
                const float* __restrict__ att_h,
                float* __restrict__ scorepart) {
    __shared__ float As[BK][BM + PAD];
    __shared__ float Bs[BK][BN + PAD];
    int tid = threadIdx.x;
    int tx = tid & 15, ty = tid >> 4;
    int m0 = blockIdx.x * BM;
    int n0 = blockIdx.y * BN;
    int lrow = tid >> 2;
    int lk4 = (tid & 3) * 4;
    float acc[4][4] = {};
    const float* Aptr = att + (size_t)(m0 + lrow) * R_ + lk4;
    bool bvalid = (n0 + lrow) < A_;
    const float* Bptr = a2a_w + (size_t)(bvalid ? (n0 + lrow) : 0) * R_ + lk4;

    for (int k0 = 0; k0 < R_; k0 += BK) {
        float4 av = *(const float4*)(Aptr + k0);
        float4 bv = bvalid ? *(const float4*)(Bptr + k0) : make_float4(0.f, 0.f, 0.f, 0.f);
        __syncthreads();
        As[lk4 + 0][lrow] = av.x; As[lk4 + 1][lrow] = av.y;
        As[lk4 + 2][lrow] = av.z; As[lk4 + 3][lrow] = av.w;
        Bs[lk4 + 0][lrow] = bv.x; Bs[lk4 + 1][lrow] = bv.y;
        Bs[lk4 + 2][lrow] = bv.z; Bs[lk4 + 3][lrow] = bv.w;
        __syncthreads();
#pragma unroll
        for (int k = 0; k < BK; ++k) {
            float4 a = *(const float4*)&As[k][ty * 4];
            float4 b = *(const float4*)&Bs[k][tx * 4];
            acc[0][0] += a.x * b.x; acc[0][1] += a.x * b.y; acc[0][2] += a.x * b.z; acc[0][3] += a.x * b.w;
            acc[1][0] += a.y * b.x; acc[1][1] += a.y * b.y; acc[1][2] += a.y * b.z; acc[1][3] += a.y * b.w;
            acc[2][0] += a.z * b.x; acc[2][1] += a.z * b.y; acc[2][2] += a.z * b.z; acc[2][3] += a.z * b.w;
            acc[3][0] += a.w * b.x; acc[3][1] += a.w * b.y; acc[3][2] += a.w * b.z; acc[3][3] += a.w * b.w;
        }
    }

    float wv[4], bb[4];
#pragma unroll
    for (int j = 0; j < 4; ++j) {
        int n = n0 + tx * 4 + j;
        wv[j] = (n < A_) ? d2d_w[n] : 0.f;
        bb[j] = (n < A_) ? a2a_b[n] : 0.f;
    }
    int nb = blockIdx.y;
#pragma unroll
    for (int i = 0; i < 4; ++i) {
        int m = m0 + ty * 4 + i;
        float ah = att_h[m];
        float p = 0.f;
#pragma unroll
        for (int j = 0; j < 4; ++j)
            p += tanhf(acc[i][j] + bb[j] + ah) * wv[j];
        p += __shfl_xor(p, 1);
        p += __shfl_xor(p, 2);
        p += __shfl_xor(p, 4);
        p += __shfl_xor(p, 8);
        if (tx == 0) scorepart[(size_t)m * 4 + nb] = p;
    }
}

// ---------------- kernel 3: softmax over i per batch ---------------------------
__global__ void softmax_kernel(const float* __restrict__ scorepart,
                               const float* __restrict__ d2d_b,
                               float* __restrict__ weight) {
    int b = blockIdx.x;
    int i = threadIdx.x;
    __shared__ float red[256];
    float sval = 0.f;
    float s = -1e30f;
    if (i < A_) {
        const float* sp = scorepart + (size_t)(b * A_ + i) * 4;
        sval = sp[0] + sp[1] + sp[2] + sp[3] + d2d_b[0];
        s = sval;
    }
    red[i] = s; __syncthreads();
    for (int off = 128; off > 0; off >>= 1) {
        if (i < off) red[i] = fmaxf(red[i], red[i + off]);
        __syncthreads();
    }
    float mx = red[0]; __syncthreads();
    float e = (i < A_) ? expf(sval - mx) : 0.f;
    red[i] = e; __syncthreads();
    for (int off = 128; off > 0; off >>= 1) {
        if (i < off) red[i] += red[i + off];
        __syncthreads();
    }
    float inv = 1.f / red[0];
    if (i < A_) weight[b * A_ + i] = e * inv;
}

// ---------------- kernel 4: att_res[b,r] = sum_i att[b,i,r] * weight[b,i] ------
__global__ void att_res_kernel(const float* __restrict__ att,
                               const float* __restrict__ weight,
                               float* __restrict__ att_res) {
    int b = blockIdx.y;
    int r = blockIdx.x * 256 + threadIdx.x;
    __shared__ float w[A_];
    if (threadIdx.x < A_) w[threadIdx.x] = weight[b * A_ + threadIdx.x];
    __syncthreads();
    const float* ap = att + (size_t)b * A_ * R_ + r;
    float acc = 0.f;
#pragma unroll 4
    for (int i = 0; i < A_; ++i) acc += ap[(size_t)i * R_] * w[i];
    att_res[b * R_ + r] = acc;
}

// ---------------- kernel 5: sums GEMM (3 matmuls summed) -----------------------
__global__ __launch_bounds__(256)
void sums_gemm(const float* __restrict__ x,
               const float* __restrict__ prev_h,
               const float* __restrict__ att_res,
               const float* __restrict__ i2h_w,
               const float* __restrict__ h2h_w,
               const float* __restrict__ r2a_w,
               const float* __restrict__ i2h_b,
               const float* __restrict__ h2h_b,
               const float* __restrict__ r2a_b,
               float* __restrict__ sums) {
    __shared__ float As[BK][BM + PAD];
    __shared__ float Bs[BK][BN + PAD];
    int tid = threadIdx.x;
    int tx = tid & 15, ty = tid >> 4;
    int m0 = blockIdx.x * BM;
    int n0 = blockIdx.y * BN;
    int lrow = tid >> 2;
    int lk4 = (tid & 3) * 4;
    float acc[4][4] = {};
    const float* Alist[3] = {x, prev_h, att_res};
    const float* Blist[3] = {i2h_w, h2h_w, r2a_w};
    for (int p = 0; p < 3; ++p) {
        const float* Aptr = Alist[p] + (size_t)(m0 + lrow) * R_ + lk4;
        const float* Bptr = Blist[p] + (size_t)(n0 + lrow) * R_ + lk4;
        for (int k0 = 0; k0 < R_; k0 += BK) {
            float4 av = *(const float4*)(Aptr + k0);
            float4 bv = *(const float4*)(Bptr + k0);
            __syncthreads();
            As[lk4 + 0][lrow] = av.x; As[lk4 + 1][lrow] = av.y;
            As[lk4 + 2][lrow] = av.z; As[lk4 + 3][lrow] = av.w;
            Bs[lk4 + 0][lrow] = bv.x; Bs[lk4 + 1][lrow] = bv.y;
            Bs[lk4 + 2][lrow] = bv.z; Bs[lk4 + 3][lrow] = bv.w;
            __syncthreads();
#pragma unroll
            for (int k = 0; k < BK; ++k) {
                float4 a = *(const float4*)&As[k][ty * 4];
                float4 b = *(const float4*)&Bs[k][tx * 4];
                acc[0][0] += a.x * b.x; acc[0][1] += a.x * b.y; acc[0][2] += a.x * b.z; acc[0][3] += a.x * b.w;
                acc[1][0] += a.y * b.x; acc[1][1] += a.y * b.y; acc[1][2] += a.y * b.z; acc[1][3] += a.y * b.w;
                acc[2][0] += a.z * b.x; acc[2][1] += a.z * b.y; acc[2][2] += a.z * b.z; acc[2][3] += a.z * b.w;
                acc[3][0] += a.w * b.x; acc[3][1] += a.w * b.y; acc[3][2] += a.w * b.z; acc[3][3] += a.w * b.w;
            }
        }
    }
#pragma unroll
    for (int i = 0; i < 4; ++i) {
        int m = m0 + ty * 4 + i;
#pragma unroll
        for (int j = 0; j < 4; ++j) {
            int n = n0 + tx * 4 + j;
            sums[(size_t)m * G4 + n] = acc[i][j] + i2h_b[n] + h2h_b[n] + r2a_b[n];
        }
    }
}

// ---------------- kernel 6: LSTM gates ----------------------------------------
__global__ void gates_kernel(const float* __restrict__ sums,
                             const float* __restrict__ prev_c,
                             float* __restrict__ out_c,
                             float* __restrict__ out_h,
                             float* __restrict__ next_h_ws) {
    int idx = blockIdx.x * 256 + threadIdx.x;
    int b = idx >> 10, r = idx & 1023;
    const float* s = sums + (size_t)b * G4;
    float ig = 1.f / (1.f + expf(-s[r]));
    float fg = 1.f / (1.f + expf(-s[R_ + r]));
    float og = 1.f / (1.f + expf(-s[2 * R_ + r]));
    float it = tanhf(s[3 * R_ + r]);
    float nc = fg * prev_c[idx] + ig * it;
    float nh = og * tanhf(nc);
    out_c[idx] = nc;
    out_h[idx] = nh;
    next_h_ws[idx] = nh;
}

// ---------------- kernel 7: proj GEMM -----------------------------------------
__global__ __launch_bounds__(256)
void proj_gemm(const float* __restrict__ next_h,
               const float* __restrict__ proj_w,
               const float* __restrict__ proj_b,
               float* __restrict__ logits) {
    __shared__ float As[BK][BM + PAD];
    __shared__ float Bs[BK][BN + PAD];
    int tid = threadIdx.x;
    int tx = tid & 15, ty = tid >> 4;
    int m0 = blockIdx.x * BM;
    int n0 = blockIdx.y * BN;
    int lrow = tid >> 2;
    int lk4 = (tid & 3) * 4;
    float acc[4][4] = {};
    const float* Aptr = next_h + (size_t)(m0 + lrow) * R_ + lk4;
    bool bvalid = (n0 + lrow) < V_;
    const float* Bptr = proj_w + (size_t)(bvalid ? (n0 + lrow) : 0) * R_ + lk4;
    for (int k0 = 0; k0 < R_; k0 += BK) {
        float4 av = *(const float4*)(Aptr + k0);
        float4 bv = bvalid ? *(const float4*)(Bptr + k0) : make_float4(0.f, 0.f, 0.f, 0.f);
        __syncthreads();
        As[lk4 + 0][lrow] = av.x; As[lk4 + 1][lrow] = av.y;
        As[lk4 + 2][lrow] = av.z; As[lk4 + 3][lrow] = av.w;
        Bs[lk4 + 0][lrow] = bv.x; Bs[lk4 + 1][lrow] = bv.y;
        Bs[lk4 + 2][lrow] = bv.z; Bs[lk4 + 3][lrow] = bv.w;
        __syncthreads();
#pragma unroll
        for (int k = 0; k < BK; ++k) {
            float4 a = *(const float4*)&As[k][ty * 4];
            float4 b = *(const float4*)&Bs[k][tx * 4];
            acc[0][0] += a.x * b.x; acc[0][1] += a.x * b.y; acc[0][2] += a.x * b.z; acc[0][3] += a.x * b.w;
            acc[1][0] += a.y * b.x; acc[1][1] += a.y * b.y; acc[1][2] += a.y * b.z; acc[1][3] += a.y * b.w;
            acc[2][0] += a.z * b.x; acc[2][1] += a.z * b.y; acc[2][2] += a.z * b.z; acc[2][3] += a.z * b.w;
            acc[3][0] += a.w * b.x; acc[3][1] += a.w * b.y; acc[3][2] += a.w * b.z; acc[3][3] += a.w * b.w;
        }
    }
#pragma unroll
    for (int i = 0; i < 4; ++i) {
        int m = m0 + ty * 4 + i;
#pragma unroll
        for (int j = 0; j < 4; ++j) {
            int n = n0 + tx * 4 + j;
            if (n < V_) logits[(size_t)m * V_ + n] = acc[i][j] + proj_b[n];
        }
    }
}

// ---------------- kernel 8: log_softmax over V per row -------------------------
__global__ void logsoftmax_kernel(const float* __restrict__ logits,
                                  float* __restrict__ out) {
    int b = blockIdx.x, t = threadIdx.x;
    __shared__ float red[256];
    const float* lp = logits + (size_t)b * V_;
    float mx = -1e30f;
    for (int v = t; v < V_; v += 256) mx = fmaxf(mx, lp[v]);
    red[t] = mx; __syncthreads();
    for (int off = 128; off > 0; off >>= 1) {
        if (t < off) red[t] = fmaxf(red[t], red[t + off]);
        __syncthreads();
    }
    mx = red[0]; __syncthreads();
    float s = 0.f;
    for (int v = t; v < V_; v += 256) s += expf(lp[v] - mx);
    red[t] = s; __syncthreads();
    for (int off = 128; off > 0; off >>= 1) {
        if (t < off) red[t] += red[t + off];
        __syncthreads();
    }
    float lse = mx + logf(red[0]);
    float* op = out + (size_t)b * V_;
    for (int v = t; v < V_; v += 256) op[v] = lp[v] - lse;
}

extern "C" void kernel_launch(void* const* d_in, const int* in_sizes, int n_in,
                              void* d_out, int out_size, void* d_ws, size_t ws_size,
                              hipStream_t stream) {
    const float* x      = (const float*)d_in[0];
    const float* att    = (const float*)d_in[1];
    const float* prev_c = (const float*)d_in[2];
    const float* prev_h = (const float*)d_in[3];
    const float* a2a_w  = (const float*)d_in[4];
    const float* a2a_b  = (const float*)d_in[5];
    const float* h2a_w  = (const float*)d_in[6];
    const float* h2a_b  = (const float*)d_in[7];
    const float* d2d_w  = (const float*)d_in[8];
    const float* d2d_b  = (const float*)d_in[9];
    const float* i2h_w  = (const float*)d_in[10];
    const float* i2h_b  = (const float*)d_in[11];
    const float* h2h_w  = (const float*)d_in[12];
    const float* h2h_b  = (const float*)d_in[13];
    const float* r2a_w  = (const float*)d_in[14];
    const float* r2a_b  = (const float*)d_in[15];
    const float* proj_w = (const float*)d_in[16];
    const float* proj_b = (const float*)d_in[17];

    float* ws        = (float*)d_ws;
    float* att_h     = ws + OFF_ATTH;
    float* scorepart = ws + OFF_SCOREPART;
    float* weight    = ws + OFF_WEIGHT;
    float* att_res   = ws + OFF_ATTRES;
    float* sums      = ws + OFF_SUMS;
    float* next_h    = ws + OFF_NEXTH;
    float* logits    = ws + OFF_LOGITS;
    float* out       = (float*)d_out;

    att_h_kernel<<<dim3(A_, B_), 64, 0, stream>>>(prev_h, h2a_w, h2a_b, att_h);
    score_gemm<<<dim3(M_ / BM, (A_ + BN - 1) / BN), 256, 0, stream>>>(
        att, a2a_w, a2a_b, d2d_w, att_h, scorepart);
    softmax_kernel<<<B_, 256, 0, stream>>>(scorepart, d2d_b, weight);
    att_res_kernel<<<dim3(R_ / 256, B_), 256, 0, stream>>>(att, weight, att_res);
    sums_gemm<<<dim3(B_ / BM, G4 / BN), 256, 0, stream>>>(
        x, prev_h, att_res, i2h_w, h2h_w, r2a_w, i2h_b, h2h_b, r2a_b, sums);
    gates_kernel<<<(B_ * R_) / 256, 256, 0, stream>>>(sums, prev_c, out, out + B_ * R_, next_h);
    proj_gemm<<<dim3(B_ / BM, (V_ + BN - 1) / BN), 256, 0, stream>>>(
        next_h, proj_w, proj_b, logits);
    logsoftmax_kernel<<<B_, 256, 0, stream>>>(logits, out + 2 * B_ * R_);
}

// Round 2
// 696.230 us; speedup vs baseline: 1.4772x; 1.4772x over previous
//
#include <hip/hip_runtime.h>
#include <math.h>

#define B_ 256
#define A_ 196
#define R_ 1024
#define V_ 10000
#define G4 4096
#define M_ (B_ * A_)   // 50176

typedef __bf16 bf16x8 __attribute__((ext_vector_type(8)));
typedef float f32x4 __attribute__((ext_vector_type(4)));

// ws layout in floats (total ~16.4 MB, fits prior footprint)
#define OFF_ATTH   0
#define OFF_SCORE  50176
#define OFF_WEIGHT (OFF_SCORE + 50176)
#define OFF_ATTRES (OFF_WEIGHT + 50176)
#define OFF_SUMS   (OFF_ATTRES + 262144)
#define OFF_NHBF   (OFF_SUMS + 1048576)     // 262144 bf16 = 131072 floats
#define OFF_LOGITS (OFF_NHBF + 131072)

__device__ __forceinline__ bf16x8 cvt8(const float* src) {
    float4 f0 = *(const float4*)src;
    float4 f1 = *(const float4*)(src + 4);
    bf16x8 v;
    v[0] = (__bf16)f0.x; v[1] = (__bf16)f0.y; v[2] = (__bf16)f0.z; v[3] = (__bf16)f0.w;
    v[4] = (__bf16)f1.x; v[5] = (__bf16)f1.y; v[6] = (__bf16)f1.z; v[7] = (__bf16)f1.w;
    return v;
}

// ---------------- kernel 1: att_h = prev_h @ h2a_w.T + h2a_b  [B, A] ----------
__global__ void att_h_kernel(const float* __restrict__ prev_h,
                             const float* __restrict__ h2a_w,
                             const float* __restrict__ h2a_b,
                             float* __restrict__ att_h) {
    int a = blockIdx.x;
    int b = blockIdx.y;
    int lane = threadIdx.x;
    const float* hp = prev_h + (size_t)b * R_;
    const float* wp = h2a_w + (size_t)a * R_;
    float s = 0.f;
    for (int k = lane; k < R_; k += 64) s += hp[k] * wp[k];
    for (int off = 32; off > 0; off >>= 1) s += __shfl_xor(s, off);
    if (lane == 0) att_h[b * A_ + a] = s + h2a_b[a];
}

// ---------------- kernel 2: attention GEMM (MFMA) + tanh/d2d epilogue ---------
// score[m] = sum_n tanh(att[m,:].a2a_w[n,:] + a2a_b[n] + att_h[m]) * d2d_w[n]
// BM=128 (4 waves x 2 m-tiles), all N=208 (13 n-tiles) per block, BK=32.
__global__ __launch_bounds__(256)
void score_gemm_mfma(const float* __restrict__ att,
                     const float* __restrict__ a2a_w,
                     const float* __restrict__ a2a_b,
                     const float* __restrict__ d2d_w,
                     const float* __restrict__ att_h,
                     float* __restrict__ score) {
    __shared__ alignas(16) __bf16 As[128][40];
    __shared__ alignas(16) __bf16 Bs[208][40];
    int tid = threadIdx.x;
    int m0 = blockIdx.x * 128;
    int lane = tid & 63;
    int w = tid >> 6;
    int ln = lane & 15;
    int quad = lane >> 4;

    f32x4 acc0[13], acc1[13];
#pragma unroll
    for (int t = 0; t < 13; ++t) {
        acc0[t] = {0.f, 0.f, 0.f, 0.f};
        acc1[t] = {0.f, 0.f, 0.f, 0.f};
    }

    for (int k0 = 0; k0 < R_; k0 += 32) {
        __syncthreads();
        // stage A: 128 rows x 32 k (512 chunks of 8)
#pragma unroll
        for (int i = 0; i < 2; ++i) {
            int c = tid + i * 256;
            int row = c >> 2, kq = (c & 3) * 8;
            bf16x8 v = cvt8(att + (size_t)(m0 + row) * R_ + k0 + kq);
            *(bf16x8*)&As[row][kq] = v;
        }
        // stage B: 208 rows x 32 k (832 chunks of 8)
#pragma unroll
        for (int i = 0; i < 4; ++i) {
            int c = tid + i * 256;
            if (c < 832) {
                int row = c >> 2, kq = (c & 3) * 8;
                bf16x8 v;
                if (row < A_) {
                    v = cvt8(a2a_w + (size_t)row * R_ + k0 + kq);
                } else {
#pragma unroll
                    for (int j = 0; j < 8; ++j) v[j] = (__bf16)0.f;
                }
                *(bf16x8*)&Bs[row][kq] = v;
            }
        }
        __syncthreads();
        bf16x8 a0 = *(bf16x8*)&As[w * 32 + ln][quad * 8];
        bf16x8 a1 = *(bf16x8*)&As[w * 32 + 16 + ln][quad * 8];
#pragma unroll
        for (int t = 0; t < 13; ++t) {
            bf16x8 b = *(bf16x8*)&Bs[t * 16 + ln][quad * 8];
            acc0[t] = __builtin_amdgcn_mfma_f32_16x16x32_bf16(a0, b, acc0[t], 0, 0, 0);
            acc1[t] = __builtin_amdgcn_mfma_f32_16x16x32_bf16(a1, b, acc1[t], 0, 0, 0);
        }
    }

    // epilogue: tanh + weighted reduce over n
    float wv[13], bb[13];
#pragma unroll
    for (int t = 0; t < 13; ++t) {
        int n = t * 16 + ln;
        wv[t] = (n < A_) ? d2d_w[n] : 0.f;
        bb[t] = (n < A_) ? a2a_b[n] : 0.f;
    }
#pragma unroll
    for (int half = 0; half < 2; ++half) {
#pragma unroll
        for (int r = 0; r < 4; ++r) {
            int m = m0 + w * 32 + half * 16 + quad * 4 + r;
            float ah = att_h[m];
            float p = 0.f;
#pragma unroll
            for (int t = 0; t < 13; ++t) {
                float v = half ? acc1[t][r] : acc0[t][r];
                p += tanhf(v + bb[t] + ah) * wv[t];
            }
            p += __shfl_xor(p, 1);
            p += __shfl_xor(p, 2);
            p += __shfl_xor(p, 4);
            p += __shfl_xor(p, 8);
            if (ln == 0) score[m] = p;
        }
    }
}

// ---------------- kernel 3: softmax over i per batch ---------------------------
__global__ void softmax_kernel(const float* __restrict__ score,
                               const float* __restrict__ d2d_b,
                               float* __restrict__ weight) {
    int b = blockIdx.x;
    int i = threadIdx.x;
    __shared__ float red[256];
    float sval = 0.f;
    float s = -1e30f;
    if (i < A_) {
        sval = score[b * A_ + i] + d2d_b[0];
        s = sval;
    }
    red[i] = s; __syncthreads();
    for (int off = 128; off > 0; off >>= 1) {
        if (i < off) red[i] = fmaxf(red[i], red[i + off]);
        __syncthreads();
    }
    float mx = red[0]; __syncthreads();
    float e = (i < A_) ? expf(sval - mx) : 0.f;
    red[i] = e; __syncthreads();
    for (int off = 128; off > 0; off >>= 1) {
        if (i < off) red[i] += red[i + off];
        __syncthreads();
    }
    float inv = 1.f / red[0];
    if (i < A_) weight[b * A_ + i] = e * inv;
}

// ---------------- kernel 4: att_res[b,r] = sum_i att[b,i,r] * weight[b,i] ------
__global__ void att_res_kernel(const float* __restrict__ att,
                               const float* __restrict__ weight,
                               float* __restrict__ att_res) {
    int b = blockIdx.y;
    int r = blockIdx.x * 256 + threadIdx.x;
    __shared__ float w[A_];
    if (threadIdx.x < A_) w[threadIdx.x] = weight[b * A_ + threadIdx.x];
    __syncthreads();
    const float* ap = att + (size_t)b * A_ * R_ + r;
    float acc = 0.f;
#pragma unroll 4
    for (int i = 0; i < A_; ++i) acc += ap[(size_t)i * R_] * w[i];
    att_res[b * R_ + r] = acc;
}

// ---------------- kernel 5: sums GEMM (MFMA, 3 phases) -------------------------
__global__ __launch_bounds__(256)
void sums_gemm_mfma(const float* __restrict__ x,
                    const float* __restrict__ prev_h,
                    const float* __restrict__ att_res,
                    const float* __restrict__ i2h_w,
                    const float* __restrict__ h2h_w,
                    const float* __restrict__ r2a_w,
                    const float* __restrict__ i2h_b,
                    const float* __restrict__ h2h_b,
                    const float* __restrict__ r2a_b,
                    float* __restrict__ sums) {
    __shared__ alignas(16) __bf16 As[64][40];
    __shared__ alignas(16) __bf16 Bs[64][40];
    int tid = threadIdx.x;
    int m0 = blockIdx.x * 64, n0 = blockIdx.y * 64;
    int lane = tid & 63, w = tid >> 6, ln = lane & 15, quad = lane >> 4;
    int row = tid >> 2, kq = (tid & 3) * 8;

    f32x4 acc[4];
#pragma unroll
    for (int t = 0; t < 4; ++t) acc[t] = {0.f, 0.f, 0.f, 0.f};

    const float* Al[3] = {x, prev_h, att_res};
    const float* Bl[3] = {i2h_w, h2h_w, r2a_w};
    for (int p = 0; p < 3; ++p) {
        const float* Asrc = Al[p] + (size_t)(m0 + row) * R_ + kq;
        const float* Bsrc = Bl[p] + (size_t)(n0 + row) * R_ + kq;
        for (int k0 = 0; k0 < R_; k0 += 32) {
            __syncthreads();
            bf16x8 va = cvt8(Asrc + k0);
            bf16x8 vb = cvt8(Bsrc + k0);
            *(bf16x8*)&As[row][kq] = va;
            *(bf16x8*)&Bs[row][kq] = vb;
            __syncthreads();
            bf16x8 a = *(bf16x8*)&As[w * 16 + ln][quad * 8];
#pragma unroll
            for (int t = 0; t < 4; ++t) {
                bf16x8 b = *(bf16x8*)&Bs[t * 16 + ln][quad * 8];
                acc[t] = __builtin_amdgcn_mfma_f32_16x16x32_bf16(a, b, acc[t], 0, 0, 0);
            }
        }
    }
#pragma unroll
    for (int t = 0; t < 4; ++t) {
#pragma unroll
        for (int r = 0; r < 4; ++r) {
            int m = m0 + w * 16 + quad * 4 + r;
            int n = n0 + t * 16 + ln;
            sums[(size_t)m * G4 + n] = acc[t][r] + i2h_b[n] + h2h_b[n] + r2a_b[n];
        }
    }
}

// ---------------- kernel 6: LSTM gates ----------------------------------------
__global__ void gates_kernel(const float* __restrict__ sums,
                             const float* __restrict__ prev_c,
                             float* __restrict__ out_c,
                             float* __restrict__ out_h,
                             __bf16* __restrict__ nh_bf) {
    int idx = blockIdx.x * 256 + threadIdx.x;
    int b = idx >> 10, r = idx & 1023;
    const float* s = sums + (size_t)b * G4;
    float ig = 1.f / (1.f + expf(-s[r]));
    float fg = 1.f / (1.f + expf(-s[R_ + r]));
    float og = 1.f / (1.f + expf(-s[2 * R_ + r]));
    float it = tanhf(s[3 * R_ + r]);
    float nc = fg * prev_c[idx] + ig * it;
    float nh = og * tanhf(nc);
    out_c[idx] = nc;
    out_h[idx] = nh;
    nh_bf[idx] = (__bf16)nh;
}

// ---------------- kernel 7: proj GEMM (MFMA) -----------------------------------
__global__ __launch_bounds__(256)
void proj_gemm_mfma(const __bf16* __restrict__ nh_bf,
                    const float* __restrict__ proj_w,
                    const float* __restrict__ proj_b,
                    float* __restrict__ logits) {
    __shared__ alignas(16) __bf16 As[64][40];
    __shared__ alignas(16) __bf16 Bs[64][40];
    int tid = threadIdx.x;
    int m0 = blockIdx.x * 64, n0 = blockIdx.y * 64;
    int lane = tid & 63, w = tid >> 6, ln = lane & 15, quad = lane >> 4;
    int row = tid >> 2, kq = (tid & 3) * 8;

    f32x4 acc[4];
#pragma unroll
    for (int t = 0; t < 4; ++t) acc[t] = {0.f, 0.f, 0.f, 0.f};

    int nr = n0 + row;
    int nrc = nr < V_ ? nr : V_ - 1;   // clamp; garbage cols masked at store
    const __bf16* Asrc = nh_bf + (size_t)(m0 + row) * R_ + kq;
    const float* Bsrc = proj_w + (size_t)nrc * R_ + kq;
    for (int k0 = 0; k0 < R_; k0 += 32) {
        __syncthreads();
        bf16x8 va = *(const bf16x8*)(Asrc + k0);
        bf16x8 vb = cvt8(Bsrc + k0);
        *(bf16x8*)&As[row][kq] = va;
        *(bf16x8*)&Bs[row][kq] = vb;
        __syncthreads();
        bf16x8 a = *(bf16x8*)&As[w * 16 + ln][quad * 8];
#pragma unroll
        for (int t = 0; t < 4; ++t) {
            bf16x8 b = *(bf16x8*)&Bs[t * 16 + ln][quad * 8];
            acc[t] = __builtin_amdgcn_mfma_f32_16x16x32_bf16(a, b, acc[t], 0, 0, 0);
        }
    }
#pragma unroll
    for (int t = 0; t < 4; ++t) {
#pragma unroll
        for (int r = 0; r < 4; ++r) {
            int m = m0 + w * 16 + quad * 4 + r;
            int n = n0 + t * 16 + ln;
            if (n < V_) logits[(size_t)m * V_ + n] = acc[t][r] + proj_b[n];
        }
    }
}

// ---------------- kernel 8: log_softmax over V per row -------------------------
__global__ void logsoftmax_kernel(const float* __restrict__ logits,
                                  float* __restrict__ out) {
    int b = blockIdx.x, t = threadIdx.x;
    __shared__ float red[256];
    const float* lp = logits + (size_t)b * V_;
    float mx = -1e30f;
    for (int v = t; v < V_; v += 256) mx = fmaxf(mx, lp[v]);
    red[t] = mx; __syncthreads();
    for (int off = 128; off > 0; off >>= 1) {
        if (t < off) red[t] = fmaxf(red[t], red[t + off]);
        __syncthreads();
    }
    mx = red[0]; __syncthreads();
    float s = 0.f;
    for (int v = t; v < V_; v += 256) s += expf(lp[v] - mx);
    red[t] = s; __syncthreads();
    for (int off = 128; off > 0; off >>= 1) {
        if (t < off) red[t] += red[t + off];
        __syncthreads();
    }
    float lse = mx + logf(red[0]);
    float* op = out + (size_t)b * V_;
    for (int v = t; v < V_; v += 256) op[v] = lp[v] - lse;
}

extern "C" void kernel_launch(void* const* d_in, const int* in_sizes, int n_in,
                              void* d_out, int out_size, void* d_ws, size_t ws_size,
                              hipStream_t stream) {
    const float* x      = (const float*)d_in[0];
    const float* att    = (const float*)d_in[1];
    const float* prev_c = (const float*)d_in[2];
    const float* prev_h = (const float*)d_in[3];
    const float* a2a_w  = (const float*)d_in[4];
    const float* a2a_b  = (const float*)d_in[5];
    const float* h2a_w  = (const float*)d_in[6];
    const float* h2a_b  = (const float*)d_in[7];
    const float* d2d_w  = (const float*)d_in[8];
    const float* d2d_b  = (const float*)d_in[9];
    const float* i2h_w  = (const float*)d_in[10];
    const float* i2h_b  = (const float*)d_in[11];
    const float* h2h_w  = (const float*)d_in[12];
    const float* h2h_b  = (const float*)d_in[13];
    const float* r2a_w  = (const float*)d_in[14];
    const float* r2a_b  = (const float*)d_in[15];
    const float* proj_w = (const float*)d_in[16];
    const float* proj_b = (const float*)d_in[17];

    float* ws      = (float*)d_ws;
    float* att_h   = ws + OFF_ATTH;
    float* score   = ws + OFF_SCORE;
    float* weight  = ws + OFF_WEIGHT;
    float* att_res = ws + OFF_ATTRES;
    float* sums    = ws + OFF_SUMS;
    __bf16* nh_bf  = (__bf16*)(ws + OFF_NHBF);
    float* logits  = ws + OFF_LOGITS;
    float* out     = (float*)d_out;

    att_h_kernel<<<dim3(A_, B_), 64, 0, stream>>>(prev_h, h2a_w, h2a_b, att_h);
    score_gemm_mfma<<<M_ / 128, 256, 0, stream>>>(att, a2a_w, a2a_b, d2d_w, att_h, score);
    softmax_kernel<<<B_, 256, 0, stream>>>(score, d2d_b, weight);
    att_res_kernel<<<dim3(R_ / 256, B_), 256, 0, stream>>>(att, weight, att_res);
    sums_gemm_mfma<<<dim3(B_ / 64, G4 / 64), 256, 0, stream>>>(
        x, prev_h, att_res, i2h_w, h2h_w, r2a_w, i2h_b, h2h_b, r2a_b, sums);
    gates_kernel<<<(B_ * R_) / 256, 256, 0, stream>>>(sums, prev_c, out, out + B_ * R_, nh_bf);
    proj_gemm_mfma<<<dim3(B_ / 64, (V_ + 63) / 64), 256, 0, stream>>>(
        nh_bf, proj_w, proj_b, logits);
    logsoftmax_kernel<<<B_, 256, 0, stream>>>(logits, out + 2 * B_ * R_);
}

// Round 3
// 565.466 us; speedup vs baseline: 1.8189x; 1.2313x over previous
//
#include <hip/hip_runtime.h>
#include <math.h>

#define B_ 256
#define A_ 196
#define R_ 1024
#define V_ 10000
#define G4 4096
#define M_ (B_ * A_)   // 50176

typedef __bf16 bf16x8 __attribute__((ext_vector_type(8)));
typedef float f32x4 __attribute__((ext_vector_type(4)));

// ws layout in floats (~21.8 MB)
#define OFF_ATTH   0
#define OFF_SCORE  50176
#define OFF_WEIGHT 100352
#define OFF_ATTRES 150528
#define OFF_P0     412672
#define OFF_P1     1461248
#define OFF_NHBF   2509824
#define OFF_LOGITS 2640896
#define OFF_PACKA  5200896   // a2a_w bf16 [208][1024]
#define OFF_PACKH  5307392   // h2a_w bf16 [256][1024]

__device__ __forceinline__ float tanh_fast(float x) {
    float e = __expf(2.f * x);
    return 1.f - 2.f / (e + 1.f);
}
__device__ __forceinline__ float sigmoid_fast(float x) {
    return 1.f / (1.f + __expf(-x));
}

__device__ __forceinline__ bf16x8 cvt8(float4 f0, float4 f1) {
    bf16x8 v;
    v[0] = (__bf16)f0.x; v[1] = (__bf16)f0.y; v[2] = (__bf16)f0.z; v[3] = (__bf16)f0.w;
    v[4] = (__bf16)f1.x; v[5] = (__bf16)f1.y; v[6] = (__bf16)f1.z; v[7] = (__bf16)f1.w;
    return v;
}

// ---------------- kernel 0: pack a2a_w and h2a_w to bf16 (zero-padded rows) ---
__global__ void pack_kernel(const float* __restrict__ a2a_w,
                            const float* __restrict__ h2a_w,
                            __bf16* __restrict__ packA,   // [208][1024]
                            __bf16* __restrict__ packH) { // [256][1024]
    int row = blockIdx.x;
    int c = threadIdx.x * 4;
    if (row < 208) {
        float4 f = (row < A_) ? *(const float4*)(a2a_w + (size_t)row * R_ + c)
                              : make_float4(0.f, 0.f, 0.f, 0.f);
        __bf16* p = packA + (size_t)row * R_ + c;
        p[0] = (__bf16)f.x; p[1] = (__bf16)f.y; p[2] = (__bf16)f.z; p[3] = (__bf16)f.w;
    } else {
        int r2 = row - 208;
        float4 f = (r2 < A_) ? *(const float4*)(h2a_w + (size_t)r2 * R_ + c)
                             : make_float4(0.f, 0.f, 0.f, 0.f);
        __bf16* p = packH + (size_t)r2 * R_ + c;
        p[0] = (__bf16)f.x; p[1] = (__bf16)f.y; p[2] = (__bf16)f.z; p[3] = (__bf16)f.w;
    }
}

// ---------------- kernel 1: att_h = prev_h @ h2a_w.T + h2a_b  (MFMA) ----------
__global__ __launch_bounds__(256)
void att_h_gemm(const float* __restrict__ prev_h,
                const __bf16* __restrict__ packH,
                const float* __restrict__ h2a_b,
                float* __restrict__ att_h) {
    __shared__ alignas(16) __bf16 As[64][40];
    __shared__ alignas(16) __bf16 Bs[64][40];
    int tid = threadIdx.x;
    int m0 = blockIdx.x * 64, n0 = blockIdx.y * 64;
    int lane = tid & 63, w = tid >> 6, ln = lane & 15, quad = lane >> 4;
    int arow = tid >> 2, akq = (tid & 3) * 8;

    f32x4 acc[4];
#pragma unroll
    for (int t = 0; t < 4; ++t) acc[t] = {0.f, 0.f, 0.f, 0.f};

    const float* Asrc = prev_h + (size_t)(m0 + arow) * R_ + akq;
    const __bf16* Bsrc = packH + (size_t)(n0 + arow) * R_ + akq;

    float4 pa0 = *(const float4*)Asrc;
    float4 pa1 = *(const float4*)(Asrc + 4);
    bf16x8 pb = *(const bf16x8*)Bsrc;

    for (int k0 = 0; k0 < R_; k0 += 32) {
        __syncthreads();
        *(bf16x8*)&As[arow][akq] = cvt8(pa0, pa1);
        *(bf16x8*)&Bs[arow][akq] = pb;
        __syncthreads();
        if (k0 + 32 < R_) {
            pa0 = *(const float4*)(Asrc + k0 + 32);
            pa1 = *(const float4*)(Asrc + k0 + 36);
            pb = *(const bf16x8*)(Bsrc + k0 + 32);
        }
        bf16x8 a = *(bf16x8*)&As[w * 16 + ln][quad * 8];
#pragma unroll
        for (int t = 0; t < 4; ++t) {
            bf16x8 b = *(bf16x8*)&Bs[t * 16 + ln][quad * 8];
            acc[t] = __builtin_amdgcn_mfma_f32_16x16x32_bf16(a, b, acc[t], 0, 0, 0);
        }
    }
#pragma unroll
    for (int t = 0; t < 4; ++t) {
#pragma unroll
        for (int r = 0; r < 4; ++r) {
            int m = m0 + w * 16 + quad * 4 + r;
            int n = n0 + t * 16 + ln;
            if (n < A_) att_h[m * A_ + n] = acc[t][r] + h2a_b[n];
        }
    }
}

// ---------------- kernel 2: attention GEMM (MFMA) + tanh/d2d epilogue ---------
// BM=64 (4 waves x 16 rows), all N=208 (13 n-tiles), BK=32, reg-prefetch.
__global__ __launch_bounds__(256)
void score_gemm_mfma(const float* __restrict__ att,
                     const __bf16* __restrict__ packA,  // a2a_w bf16 [208][1024]
                     const float* __restrict__ a2a_b,
                     const float* __restrict__ d2d_w,
                     const float* __restrict__ att_h,
                     float* __restrict__ score) {
    __shared__ alignas(16) __bf16 As[64][40];
    __shared__ alignas(16) __bf16 Bs[208][40];
    int tid = threadIdx.x;
    int m0 = blockIdx.x * 64;
    int lane = tid & 63, w = tid >> 6, ln = lane & 15, quad = lane >> 4;
    int arow = tid >> 2, akq = (tid & 3) * 8;

    f32x4 acc[13];
#pragma unroll
    for (int t = 0; t < 13; ++t) acc[t] = {0.f, 0.f, 0.f, 0.f};

    const float* Asrc = att + (size_t)(m0 + arow) * R_ + akq;

    // B chunks: c = tid + i*256 (c < 832): brow = c>>2, bkq = (c&3)*8
    float4 pa0 = *(const float4*)Asrc;
    float4 pa1 = *(const float4*)(Asrc + 4);
    bf16x8 pb[4];
#pragma unroll
    for (int i = 0; i < 4; ++i) {
        int c = tid + i * 256;
        if (c < 832) {
            int brow = c >> 2, bkq = (c & 3) * 8;
            pb[i] = *(const bf16x8*)(packA + (size_t)brow * R_ + bkq);
        }
    }

    for (int k0 = 0; k0 < R_; k0 += 32) {
        __syncthreads();
        *(bf16x8*)&As[arow][akq] = cvt8(pa0, pa1);
#pragma unroll
        for (int i = 0; i < 4; ++i) {
            int c = tid + i * 256;
            if (c < 832) {
                int brow = c >> 2, bkq = (c & 3) * 8;
                *(bf16x8*)&Bs[brow][bkq] = pb[i];
            }
        }
        __syncthreads();
        if (k0 + 32 < R_) {
            pa0 = *(const float4*)(Asrc + k0 + 32);
            pa1 = *(const float4*)(Asrc + k0 + 36);
#pragma unroll
            for (int i = 0; i < 4; ++i) {
                int c = tid + i * 256;
                if (c < 832) {
                    int brow = c >> 2, bkq = (c & 3) * 8;
                    pb[i] = *(const bf16x8*)(packA + (size_t)brow * R_ + k0 + 32 + bkq);
                }
            }
        }
        bf16x8 a = *(bf16x8*)&As[w * 16 + ln][quad * 8];
#pragma unroll
        for (int t = 0; t < 13; ++t) {
            bf16x8 b = *(bf16x8*)&Bs[t * 16 + ln][quad * 8];
            acc[t] = __builtin_amdgcn_mfma_f32_16x16x32_bf16(a, b, acc[t], 0, 0, 0);
        }
    }

    float wv[13], bb[13];
#pragma unroll
    for (int t = 0; t < 13; ++t) {
        int n = t * 16 + ln;
        wv[t] = (n < A_) ? d2d_w[n] : 0.f;
        bb[t] = (n < A_) ? a2a_b[n] : 0.f;
    }
#pragma unroll
    for (int r = 0; r < 4; ++r) {
        int m = m0 + w * 16 + quad * 4 + r;
        float ah = att_h[m];
        float p = 0.f;
#pragma unroll
        for (int t = 0; t < 13; ++t)
            p += tanh_fast(acc[t][r] + bb[t] + ah) * wv[t];
        p += __shfl_xor(p, 1);
        p += __shfl_xor(p, 2);
        p += __shfl_xor(p, 4);
        p += __shfl_xor(p, 8);
        if (ln == 0) score[m] = p;
    }
}

// ---------------- kernel 3: softmax over i per batch ---------------------------
__global__ void softmax_kernel(const float* __restrict__ score,
                               const float* __restrict__ d2d_b,
                               float* __restrict__ weight) {
    int b = blockIdx.x;
    int i = threadIdx.x;
    __shared__ float red[256];
    float sval = 0.f;
    float s = -1e30f;
    if (i < A_) {
        sval = score[b * A_ + i] + d2d_b[0];
        s = sval;
    }
    red[i] = s; __syncthreads();
    for (int off = 128; off > 0; off >>= 1) {
        if (i < off) red[i] = fmaxf(red[i], red[i + off]);
        __syncthreads();
    }
    float mx = red[0]; __syncthreads();
    float e = (i < A_) ? __expf(sval - mx) : 0.f;
    red[i] = e; __syncthreads();
    for (int off = 128; off > 0; off >>= 1) {
        if (i < off) red[i] += red[i + off];
        __syncthreads();
    }
    float inv = 1.f / red[0];
    if (i < A_) weight[b * A_ + i] = e * inv;
}

// ---------------- kernel 4: att_res[b,r] = sum_i att[b,i,r] * weight[b,i] ------
__global__ __launch_bounds__(256)
void att_res_kernel(const float* __restrict__ att,
                    const float* __restrict__ weight,
                    float* __restrict__ att_res) {
    int b = blockIdx.x;
    int r = threadIdx.x * 4;
    __shared__ float w[A_];
    if (threadIdx.x < A_) w[threadIdx.x] = weight[b * A_ + threadIdx.x];
    __syncthreads();
    const float* ap = att + (size_t)b * A_ * R_ + r;
    float4 acc = make_float4(0.f, 0.f, 0.f, 0.f);
    // 196 = 4*49; unroll 4 for load ILP
    for (int i = 0; i < A_; i += 4) {
        float4 v0 = *(const float4*)(ap + (size_t)(i + 0) * R_);
        float4 v1 = *(const float4*)(ap + (size_t)(i + 1) * R_);
        float4 v2 = *(const float4*)(ap + (size_t)(i + 2) * R_);
        float4 v3 = *(const float4*)(ap + (size_t)(i + 3) * R_);
        float w0 = w[i], w1 = w[i + 1], w2 = w[i + 2], w3 = w[i + 3];
        acc.x += v0.x * w0 + v1.x * w1 + v2.x * w2 + v3.x * w3;
        acc.y += v0.y * w0 + v1.y * w1 + v2.y * w2 + v3.y * w3;
        acc.z += v0.z * w0 + v1.z * w1 + v2.z * w2 + v3.z * w3;
        acc.w += v0.w * w0 + v1.w * w1 + v2.w * w2 + v3.w * w3;
    }
    *(float4*)(att_res + (size_t)b * R_ + r) = acc;
}

// ---------------- kernel 5: sums GEMM (MFMA, 3 phases, split-K=2) --------------
__global__ __launch_bounds__(256)
void sums_gemm_mfma(const float* __restrict__ x,
                    const float* __restrict__ prev_h,
                    const float* __restrict__ att_res,
                    const float* __restrict__ i2h_w,
                    const float* __restrict__ h2h_w,
                    const float* __restrict__ r2a_w,
                    float* __restrict__ P0,
                    float* __restrict__ P1) {
    __shared__ alignas(16) __bf16 As[64][40];
    __shared__ alignas(16) __bf16 Bs[64][40];
    int tid = threadIdx.x;
    int m0 = blockIdx.x * 64, n0 = blockIdx.y * 64;
    int ks = blockIdx.z;
    int kbeg = ks * 512, kend = kbeg + 512;
    int lane = tid & 63, w = tid >> 6, ln = lane & 15, quad = lane >> 4;
    int arow = tid >> 2, akq = (tid & 3) * 8;

    f32x4 acc[4];
#pragma unroll
    for (int t = 0; t < 4; ++t) acc[t] = {0.f, 0.f, 0.f, 0.f};

    const float* Al[3] = {x, prev_h, att_res};
    const float* Bl[3] = {i2h_w, h2h_w, r2a_w};
    for (int p = 0; p < 3; ++p) {
        const float* Asrc = Al[p] + (size_t)(m0 + arow) * R_ + akq;
        const float* Bsrc = Bl[p] + (size_t)(n0 + arow) * R_ + akq;
        float4 pa0 = *(const float4*)(Asrc + kbeg);
        float4 pa1 = *(const float4*)(Asrc + kbeg + 4);
        float4 pb0 = *(const float4*)(Bsrc + kbeg);
        float4 pb1 = *(const float4*)(Bsrc + kbeg + 4);
        for (int k0 = kbeg; k0 < kend; k0 += 32) {
            __syncthreads();
            *(bf16x8*)&As[arow][akq] = cvt8(pa0, pa1);
            *(bf16x8*)&Bs[arow][akq] = cvt8(pb0, pb1);
            __syncthreads();
            if (k0 + 32 < kend) {
                pa0 = *(const float4*)(Asrc + k0 + 32);
                pa1 = *(const float4*)(Asrc + k0 + 36);
                pb0 = *(const float4*)(Bsrc + k0 + 32);
                pb1 = *(const float4*)(Bsrc + k0 + 36);
            }
            bf16x8 a = *(bf16x8*)&As[w * 16 + ln][quad * 8];
#pragma unroll
            for (int t = 0; t < 4; ++t) {
                bf16x8 b = *(bf16x8*)&Bs[t * 16 + ln][quad * 8];
                acc[t] = __builtin_amdgcn_mfma_f32_16x16x32_bf16(a, b, acc[t], 0, 0, 0);
            }
        }
    }
    float* P = ks ? P1 : P0;
#pragma unroll
    for (int t = 0; t < 4; ++t) {
#pragma unroll
        for (int r = 0; r < 4; ++r) {
            int m = m0 + w * 16 + quad * 4 + r;
            int n = n0 + t * 16 + ln;
            P[(size_t)m * G4 + n] = acc[t][r];
        }
    }
}

// ---------------- kernel 6: LSTM gates ----------------------------------------
__global__ void gates_kernel(const float* __restrict__ P0,
                             const float* __restrict__ P1,
                             const float* __restrict__ i2h_b,
                             const float* __restrict__ h2h_b,
                             const float* __restrict__ r2a_b,
                             const float* __restrict__ prev_c,
                             float* __restrict__ out_c,
                             float* __restrict__ out_h,
                             __bf16* __restrict__ nh_bf) {
    int idx = blockIdx.x * 256 + threadIdx.x;
    int b = idx >> 10, r = idx & 1023;
    size_t off = (size_t)b * G4;
    float s0 = P0[off + r] + P1[off + r] + i2h_b[r] + h2h_b[r] + r2a_b[r];
    float s1 = P0[off + R_ + r] + P1[off + R_ + r] + i2h_b[R_ + r] + h2h_b[R_ + r] + r2a_b[R_ + r];
    float s2 = P0[off + 2 * R_ + r] + P1[off + 2 * R_ + r] + i2h_b[2 * R_ + r] + h2h_b[2 * R_ + r] + r2a_b[2 * R_ + r];
    float s3 = P0[off + 3 * R_ + r] + P1[off + 3 * R_ + r] + i2h_b[3 * R_ + r] + h2h_b[3 * R_ + r] + r2a_b[3 * R_ + r];
    float ig = sigmoid_fast(s0);
    float fg = sigmoid_fast(s1);
    float og = sigmoid_fast(s2);
    float it = tanh_fast(s3);
    float nc = fg * prev_c[idx] + ig * it;
    float nh = og * tanh_fast(nc);
    out_c[idx] = nc;
    out_h[idx] = nh;
    nh_bf[idx] = (__bf16)nh;
}

// ---------------- kernel 7: proj GEMM (MFMA) -----------------------------------
__global__ __launch_bounds__(256)
void proj_gemm_mfma(const __bf16* __restrict__ nh_bf,
                    const float* __restrict__ proj_w,
                    const float* __restrict__ proj_b,
                    float* __restrict__ logits) {
    __shared__ alignas(16) __bf16 As[64][40];
    __shared__ alignas(16) __bf16 Bs[64][40];
    int tid = threadIdx.x;
    int m0 = blockIdx.x * 64, n0 = blockIdx.y * 64;
    int lane = tid & 63, w = tid >> 6, ln = lane & 15, quad = lane >> 4;
    int arow = tid >> 2, akq = (tid & 3) * 8;

    f32x4 acc[4];
#pragma unroll
    for (int t = 0; t < 4; ++t) acc[t] = {0.f, 0.f, 0.f, 0.f};

    int nr = n0 + arow;
    int nrc = nr < V_ ? nr : V_ - 1;
    const __bf16* Asrc = nh_bf + (size_t)(m0 + arow) * R_ + akq;
    const float* Bsrc = proj_w + (size_t)nrc * R_ + akq;

    bf16x8 pa = *(const bf16x8*)Asrc;
    float4 pb0 = *(const float4*)Bsrc;
    float4 pb1 = *(const float4*)(Bsrc + 4);

    for (int k0 = 0; k0 < R_; k0 += 32) {
        __syncthreads();
        *(bf16x8*)&As[arow][akq] = pa;
        *(bf16x8*)&Bs[arow][akq] = cvt8(pb0, pb1);
        __syncthreads();
        if (k0 + 32 < R_) {
            pa = *(const bf16x8*)(Asrc + k0 + 32);
            pb0 = *(const float4*)(Bsrc + k0 + 32);
            pb1 = *(const float4*)(Bsrc + k0 + 36);
        }
        bf16x8 a = *(bf16x8*)&As[w * 16 + ln][quad * 8];
#pragma unroll
        for (int t = 0; t < 4; ++t) {
            bf16x8 b = *(bf16x8*)&Bs[t * 16 + ln][quad * 8];
            acc[t] = __builtin_amdgcn_mfma_f32_16x16x32_bf16(a, b, acc[t], 0, 0, 0);
        }
    }
#pragma unroll
    for (int t = 0; t < 4; ++t) {
#pragma unroll
        for (int r = 0; r < 4; ++r) {
            int m = m0 + w * 16 + quad * 4 + r;
            int n = n0 + t * 16 + ln;
            if (n < V_) logits[(size_t)m * V_ + n] = acc[t][r] + proj_b[n];
        }
    }
}

// ---------------- kernel 8: log_softmax over V per row -------------------------
__global__ void logsoftmax_kernel(const float* __restrict__ logits,
                                  float* __restrict__ out) {
    int b = blockIdx.x, t = threadIdx.x;
    __shared__ float red[256];
    const float* lp = logits + (size_t)b * V_;
    float mx = -1e30f;
    for (int v = t; v < V_; v += 256) mx = fmaxf(mx, lp[v]);
    red[t] = mx; __syncthreads();
    for (int off = 128; off > 0; off >>= 1) {
        if (t < off) red[t] = fmaxf(red[t], red[t + off]);
        __syncthreads();
    }
    mx = red[0]; __syncthreads();
    float s = 0.f;
    for (int v = t; v < V_; v += 256) s += __expf(lp[v] - mx);
    red[t] = s; __syncthreads();
    for (int off = 128; off > 0; off >>= 1) {
        if (t < off) red[t] += red[t + off];
        __syncthreads();
    }
    float lse = mx + __logf(red[0]);
    float* op = out + (size_t)b * V_;
    for (int v = t; v < V_; v += 256) op[v] = lp[v] - lse;
}

extern "C" void kernel_launch(void* const* d_in, const int* in_sizes, int n_in,
                              void* d_out, int out_size, void* d_ws, size_t ws_size,
                              hipStream_t stream) {
    const float* x      = (const float*)d_in[0];
    const float* att    = (const float*)d_in[1];
    const float* prev_c = (const float*)d_in[2];
    const float* prev_h = (const float*)d_in[3];
    const float* a2a_w  = (const float*)d_in[4];
    const float* a2a_b  = (const float*)d_in[5];
    const float* h2a_w  = (const float*)d_in[6];
    const float* h2a_b  = (const float*)d_in[7];
    const float* d2d_w  = (const float*)d_in[8];
    const float* d2d_b  = (const float*)d_in[9];
    const float* i2h_w  = (const float*)d_in[10];
    const float* i2h_b  = (const float*)d_in[11];
    const float* h2h_w  = (const float*)d_in[12];
    const float* h2h_b  = (const float*)d_in[13];
    const float* r2a_w  = (const float*)d_in[14];
    const float* r2a_b  = (const float*)d_in[15];
    const float* proj_w = (const float*)d_in[16];
    const float* proj_b = (const float*)d_in[17];

    float* ws      = (float*)d_ws;
    float* att_h   = ws + OFF_ATTH;
    float* score   = ws + OFF_SCORE;
    float* weight  = ws + OFF_WEIGHT;
    float* att_res = ws + OFF_ATTRES;
    float* P0      = ws + OFF_P0;
    float* P1      = ws + OFF_P1;
    __bf16* nh_bf  = (__bf16*)(ws + OFF_NHBF);
    float* logits  = ws + OFF_LOGITS;
    __bf16* packA  = (__bf16*)(ws + OFF_PACKA);
    __bf16* packH  = (__bf16*)(ws + OFF_PACKH);
    float* out     = (float*)d_out;

    pack_kernel<<<464, 256, 0, stream>>>(a2a_w, h2a_w, packA, packH);
    att_h_gemm<<<dim3(B_ / 64, 4), 256, 0, stream>>>(prev_h, packH, h2a_b, att_h);
    score_gemm_mfma<<<M_ / 64, 256, 0, stream>>>(att, packA, a2a_b, d2d_w, att_h, score);
    softmax_kernel<<<B_, 256, 0, stream>>>(score, d2d_b, weight);
    att_res_kernel<<<B_, 256, 0, stream>>>(att, weight, att_res);
    sums_gemm_mfma<<<dim3(B_ / 64, G4 / 64, 2), 256, 0, stream>>>(
        x, prev_h, att_res, i2h_w, h2h_w, r2a_w, P0, P1);
    gates_kernel<<<(B_ * R_) / 256, 256, 0, stream>>>(
        P0, P1, i2h_b, h2h_b, r2a_b, prev_c, out, out + B_ * R_, nh_bf);
    proj_gemm_mfma<<<dim3(B_ / 64, (V_ + 63) / 64), 256, 0, stream>>>(
        nh_bf, proj_w, proj_b, logits);
    logsoftmax_kernel<<<B_, 256, 0, stream>>>(logits, out + 2 * B_ * R_);
}